// Round 5
// baseline (2580.000 us; speedup 1.0000x reference)
//
#include <hip/hip_runtime.h>
#include <hip/hip_fp16.h>

// out[r] = sum_{e: row[e]==r} val[e] * embs[col[e]]
// N_NODES = 100000, N_EDGES = 3200000, D = 128, fp32.
//
// Pipeline:
//   k_conv  : embs fp32 -> fp16, permuted so half2 packs features (f, f+64)
//   k_bhist : per-64-row-bucket edge counts
//   k_bscan : exclusive scan over buckets (<=4096 via 4 elems/thread)
//   k_part  : edges -> bucket-contiguous tmp (tmp aliases d_out)
//   k_csort : per bucket, bin edges by col-group (2048 cols) for L2 locality
//   k_accum : block per bucket, fp32 LDS accumulator (64x128 = 32 KB),
//             wave-per-edge coalesced fp16 gather + conflict-free ds_add_f32,
//             single coalesced writeout. No per-row CSR needed.

#define D_FEAT 128
#define BROWS 64             // rows per bucket
#define BSHIFT 6
#define PART_BLK 256
#define PART_EPT 16          // edges per thread in k_part
#define PART_EPB (PART_BLK * PART_EPT)   // 4096 edges per block
#define CG_SHIFT 11          // col-group = col >> 11 (2048 cols = 512 KB fp16)
#define NG 64                // max col-groups (n_nodes <= 131072 here)

// ---------- embs fp32 -> fp16, permuted: ebp[c*64+l] = (emb[c][l], emb[c][l+64]) ----------
__global__ __launch_bounds__(256) void k_conv(const float* __restrict__ embs,
                                              __half2* __restrict__ ebp,
                                              int n_nodes) {
    int i = blockIdx.x * blockDim.x + threadIdx.x;
    if (i >= n_nodes * 16) return;
    int c = i >> 4, j4 = i & 15;
    const float4* e4 = reinterpret_cast<const float4*>(embs);
    float4 lo = e4[(size_t)c * 32 + j4];        // features 4j4..4j4+3
    float4 hi = e4[(size_t)c * 32 + 16 + j4];   // features 64+4j4..
    __half2 o0 = __floats2half2_rn(lo.x, hi.x);
    __half2 o1 = __floats2half2_rn(lo.y, hi.y);
    __half2 o2 = __floats2half2_rn(lo.z, hi.z);
    __half2 o3 = __floats2half2_rn(lo.w, hi.w);
    int4 w = make_int4(*(int*)&o0, *(int*)&o1, *(int*)&o2, *(int*)&o3);
    reinterpret_cast<int4*>(ebp)[(size_t)c * 16 + j4] = w;
}

// ---------- bucket histogram (LDS-aggregated) ----------
__global__ __launch_bounds__(PART_BLK) void k_bhist(const int* __restrict__ row,
                                                    int* __restrict__ bcnt,
                                                    int n_edges, int nb) {
    extern __shared__ int lcnt[];
    for (int j = threadIdx.x; j < nb; j += PART_BLK) lcnt[j] = 0;
    __syncthreads();
    int base = blockIdx.x * PART_EPB;
#pragma unroll
    for (int k = 0; k < PART_EPT; ++k) {
        int e = base + k * PART_BLK + threadIdx.x;
        if (e < n_edges) atomicAdd(&lcnt[row[e] >> BSHIFT], 1);
    }
    __syncthreads();
    for (int j = threadIdx.x; j < nb; j += PART_BLK)
        if (lcnt[j]) atomicAdd(&bcnt[j], lcnt[j]);
}

// ---------- exclusive scan over nb (<=4096) buckets, one block ----------
__global__ __launch_bounds__(1024) void k_bscan(const int* __restrict__ bcnt,
                                                int* __restrict__ bstart,
                                                int* __restrict__ gcur, int nb) {
    __shared__ int s[1024];
    int t = threadIdx.x;
    if (nb > 4096) {            // safety fallback (not expected)
        if (t == 0) {
            int a = 0;
            for (int i = 0; i < nb; ++i) { bstart[i] = a; gcur[i] = a; a += bcnt[i]; }
            bstart[nb] = a;
        }
        return;
    }
    int base = t * 4;
    int c[4];
#pragma unroll
    for (int k = 0; k < 4; ++k) c[k] = (base + k < nb) ? bcnt[base + k] : 0;
    int tsum = c[0] + c[1] + c[2] + c[3];
    s[t] = tsum;
    __syncthreads();
    for (int off = 1; off < 1024; off <<= 1) {
        int u = (t >= off) ? s[t - off] : 0;
        __syncthreads();
        s[t] += u;
        __syncthreads();
    }
    int ex = s[t] - tsum;
#pragma unroll
    for (int k = 0; k < 4; ++k) {
        if (base + k < nb) { bstart[base + k] = ex; gcur[base + k] = ex; ex += c[k]; }
    }
    if (t == 1023) bstart[nb] = s[1023];
}

// ---------- binned partition: edges -> bucket-contiguous tmp ----------
__global__ __launch_bounds__(PART_BLK) void k_part(const int* __restrict__ row,
                                                   const int* __restrict__ col,
                                                   const float* __restrict__ val,
                                                   int* __restrict__ gcur,
                                                   int2* __restrict__ tmp,
                                                   int n_edges, int nb) {
    extern __shared__ int sm[];
    int* lcnt  = sm;
    int* lbase = sm + nb;
    int* lcur  = sm + 2 * nb;
    for (int j = threadIdx.x; j < nb; j += PART_BLK) { lcnt[j] = 0; lcur[j] = 0; }
    __syncthreads();

    int base = blockIdx.x * PART_EPB;
    int r[PART_EPT], c[PART_EPT];
    float v[PART_EPT];
#pragma unroll
    for (int k = 0; k < PART_EPT; ++k) {
        int e = base + k * PART_BLK + threadIdx.x;
        r[k] = -1;
        if (e < n_edges) {
            r[k] = row[e]; c[k] = col[e]; v[k] = val[e];
            atomicAdd(&lcnt[r[k] >> BSHIFT], 1);
        }
    }
    __syncthreads();
    for (int j = threadIdx.x; j < nb; j += PART_BLK)
        if (lcnt[j]) lbase[j] = atomicAdd(&gcur[j], lcnt[j]);
    __syncthreads();
#pragma unroll
    for (int k = 0; k < PART_EPT; ++k) {
        if (r[k] >= 0) {
            int b = r[k] >> BSHIFT;
            int rank = atomicAdd(&lcur[b], 1);
            tmp[lbase[b] + rank] =
                make_int2(((r[k] & (BROWS - 1)) << 24) | c[k], __float_as_int(v[k]));
        }
    }
}

// ---------- per-bucket col-group ordering (gather locality) ----------
__global__ __launch_bounds__(256) void k_csort(const int2* __restrict__ tmp,
                                               const int* __restrict__ bstart,
                                               int2* __restrict__ pcv) {
    __shared__ int gc[NG], gs[NG], gq[NG];
    int b = blockIdx.x;
    int base = bstart[b];
    int nE = bstart[b + 1] - base;
    int tid = threadIdx.x;

    if (tid < NG) { gc[tid] = 0; gq[tid] = 0; }
    __syncthreads();
    for (int i = tid; i < nE; i += 256) {
        int c = tmp[base + i].x & 0xFFFFFF;
        int g = c >> CG_SHIFT; if (g > NG - 1) g = NG - 1;
        atomicAdd(&gc[g], 1);
    }
    __syncthreads();
    if (tid < NG) gs[tid] = gc[tid];
    __syncthreads();
    for (int off = 1; off < NG; off <<= 1) {
        int u = (tid < NG && tid >= off) ? gs[tid - off] : 0;
        __syncthreads();
        if (tid < NG) gs[tid] += u;
        __syncthreads();
    }
    if (tid < NG) gs[tid] -= gc[tid];   // exclusive
    __syncthreads();
    for (int i = tid; i < nE; i += 256) {
        int2 p = tmp[base + i];
        int c = p.x & 0xFFFFFF;
        int g = c >> CG_SHIFT; if (g > NG - 1) g = NG - 1;
        int rank = atomicAdd(&gq[g], 1);
        pcv[base + gs[g] + rank] = p;
    }
}

// ---------- accumulate: block per bucket, fp32 LDS accumulator ----------
__global__ __launch_bounds__(256) void k_accum(const int2* __restrict__ pcv,
                                               const int* __restrict__ bstart,
                                               const __half2* __restrict__ ebp,
                                               float* __restrict__ out, int n_nodes) {
    __shared__ float acc[BROWS * D_FEAT];    // 32 KB
    int tid = threadIdx.x;
    int wave = tid >> 6;
    int lane = tid & 63;

    float4 z = make_float4(0.f, 0.f, 0.f, 0.f);
    for (int idx = tid; idx < BROWS * D_FEAT / 4; idx += 256)
        reinterpret_cast<float4*>(acc)[idx] = z;
    __syncthreads();

    int b = blockIdx.x;
    int base = bstart[b];
    int end  = bstart[b + 1];

    int i = base + wave;
    for (; i + 12 < end; i += 16) {
        int2 p0 = pcv[i], p1 = pcv[i + 4], p2 = pcv[i + 8], p3 = pcv[i + 12];
        unsigned x0 = p0.x, x1 = p1.x, x2 = p2.x, x3 = p3.x;
        __half2 h0 = ebp[(size_t)(x0 & 0xFFFFFF) * 64 + lane];
        __half2 h1 = ebp[(size_t)(x1 & 0xFFFFFF) * 64 + lane];
        __half2 h2 = ebp[(size_t)(x2 & 0xFFFFFF) * 64 + lane];
        __half2 h3 = ebp[(size_t)(x3 & 0xFFFFFF) * 64 + lane];
        float v0 = __int_as_float(p0.y), v1 = __int_as_float(p1.y);
        float v2 = __int_as_float(p2.y), v3 = __int_as_float(p3.y);
        float2 f0 = __half22float2(h0), f1 = __half22float2(h1);
        float2 f2 = __half22float2(h2), f3 = __half22float2(h3);
        atomicAdd(&acc[(x0 >> 24) * D_FEAT + lane],      v0 * f0.x);
        atomicAdd(&acc[(x0 >> 24) * D_FEAT + 64 + lane], v0 * f0.y);
        atomicAdd(&acc[(x1 >> 24) * D_FEAT + lane],      v1 * f1.x);
        atomicAdd(&acc[(x1 >> 24) * D_FEAT + 64 + lane], v1 * f1.y);
        atomicAdd(&acc[(x2 >> 24) * D_FEAT + lane],      v2 * f2.x);
        atomicAdd(&acc[(x2 >> 24) * D_FEAT + 64 + lane], v2 * f2.y);
        atomicAdd(&acc[(x3 >> 24) * D_FEAT + lane],      v3 * f3.x);
        atomicAdd(&acc[(x3 >> 24) * D_FEAT + 64 + lane], v3 * f3.y);
    }
    for (; i < end; i += 4) {
        int2 p = pcv[i];
        unsigned x = p.x;
        __half2 h = ebp[(size_t)(x & 0xFFFFFF) * 64 + lane];
        float v = __int_as_float(p.y);
        float2 f = __half22float2(h);
        atomicAdd(&acc[(x >> 24) * D_FEAT + lane],      v * f.x);
        atomicAdd(&acc[(x >> 24) * D_FEAT + 64 + lane], v * f.y);
    }
    __syncthreads();

    int row0 = b << BSHIFT;
    float4* out4 = reinterpret_cast<float4*>(out);
    for (int idx = tid; idx < BROWS * (D_FEAT / 4); idx += 256) {
        int lr = idx >> 5;          // local row
        int q  = idx & 31;          // float4 within row
        if (row0 + lr < n_nodes)
            out4[(size_t)(row0 + lr) * 32 + q] =
                reinterpret_cast<float4*>(acc)[lr * 32 + q];
    }
}

// ---------- fallback: atomic scatter ----------
__global__ void gcn_scatter_atomic(const int* __restrict__ edge_row,
                                   const int* __restrict__ edge_col,
                                   const float* __restrict__ edge_val,
                                   const float* __restrict__ embs,
                                   float* __restrict__ out, int n_edges) {
    long long tid = (long long)blockIdx.x * blockDim.x + threadIdx.x;
    int sub = (int)(tid & 31);
    long long edge = tid >> 5;
    if (edge >= n_edges) return;
    int r = edge_row[edge];
    int c = edge_col[edge];
    float v = edge_val[edge];
    const float4* src = reinterpret_cast<const float4*>(embs + (size_t)c * D_FEAT);
    float4 m = src[sub];
    float* dst = out + (size_t)r * D_FEAT + (size_t)sub * 4;
    atomicAdd(dst + 0, m.x * v);
    atomicAdd(dst + 1, m.y * v);
    atomicAdd(dst + 2, m.z * v);
    atomicAdd(dst + 3, m.w * v);
}

extern "C" void kernel_launch(void* const* d_in, const int* in_sizes, int n_in,
                              void* d_out, int out_size, void* d_ws, size_t ws_size,
                              hipStream_t stream) {
    const int*   edge_row = (const int*)d_in[0];
    const int*   edge_col = (const int*)d_in[1];
    const float* edge_val = (const float*)d_in[2];
    const float* embs     = (const float*)d_in[3];
    float*       out      = (float*)d_out;

    const int n_edges = in_sizes[0];
    const int n_nodes = out_size / D_FEAT;
    const int nb = (n_nodes + BROWS - 1) >> BSHIFT;

    // Workspace layout
    char* ws = (char*)d_ws;
    const size_t off_pcv    = 0;
    const size_t off_bcnt   = off_pcv + (size_t)n_edges * 8;
    const size_t off_bstart = off_bcnt + (size_t)nb * 4;
    const size_t off_gcur   = off_bstart + (size_t)(nb + 1) * 4;
    const size_t off_embs16 = (off_gcur + (size_t)nb * 4 + 15) & ~(size_t)15;
    const size_t full_ws    = off_embs16 + (size_t)n_nodes * D_FEAT * 2;

    // tmp aliases d_out (consumed by k_csort before k_accum writes out).
    bool tmp_fits = ((size_t)n_edges * 8 <= (size_t)out_size * 4);
    bool cols_fit = (n_nodes <= (NG << CG_SHIFT)) && (n_nodes <= (1 << 24));

    if (ws_size < full_ws || !tmp_fits || !cols_fit || nb > 4096) {
        hipMemsetAsync(d_out, 0, (size_t)out_size * sizeof(float), stream);
        long long total = (long long)n_edges * 32;
        int blocks = (int)((total + 255) / 256);
        gcn_scatter_atomic<<<blocks, 256, 0, stream>>>(edge_row, edge_col, edge_val,
                                                       embs, out, n_edges);
        return;
    }

    int2*    pcv    = (int2*)(ws + off_pcv);
    int*     bcnt   = (int*)(ws + off_bcnt);
    int*     bstart = (int*)(ws + off_bstart);
    int*     gcur   = (int*)(ws + off_gcur);
    __half2* ebp    = (__half2*)(ws + off_embs16);
    int2*    tmp    = (int2*)d_out;

    hipMemsetAsync(bcnt, 0, (size_t)nb * 4, stream);

    const int nchunks = (n_edges + PART_EPB - 1) / PART_EPB;

    k_conv<<<(n_nodes * 16 + 255) / 256, 256, 0, stream>>>(embs, ebp, n_nodes);
    k_bhist<<<nchunks, PART_BLK, (size_t)nb * 4, stream>>>(edge_row, bcnt, n_edges, nb);
    k_bscan<<<1, 1024, 0, stream>>>(bcnt, bstart, gcur, nb);
    k_part<<<nchunks, PART_BLK, (size_t)nb * 12, stream>>>(edge_row, edge_col, edge_val,
                                                           gcur, tmp, n_edges, nb);
    k_csort<<<nb, 256, 0, stream>>>(tmp, bstart, pcv);
    k_accum<<<nb, 256, 0, stream>>>(pcv, bstart, ebp, out, n_nodes);
}

// Round 6
// 390.271 us; speedup vs baseline: 6.6108x; 6.6108x over previous
//
#include <hip/hip_runtime.h>
#include <hip/hip_fp16.h>

// out[r] = sum_{e: row[e]==r} val[e] * embs[col[e]]
// N_NODES = 100000, N_EDGES = 3200000, D = 128, fp32.
//
// Pipeline:
//   k_conv  : embs fp32 -> fp16 (pairs (f,f+1) per half2)
//   k_hist  : coarse-bucket (512 rows) edge counts
//   k_cscan : exclusive scan over nbc (<=256) coarse buckets
//   k_part1 : LDS-staged partition, coalesced ~170B runs into tmp1 (= d_out alias)
//   k_part2 : block per coarse bucket: LDS row-hist + scan -> row-sorted pcv
//             + row_start/row_cnt. (Replaces old scatter2; int LDS atomics only —
//             fp32 LDS atomics compile to CAS loops here: 15x regression in R5.)
//   k_rows_h: one wave per row, register accumulate, fp16 gathers (R4-proven).

#define D_FEAT 128
#define CSHIFT 9             // 512 rows per coarse bucket
#define CROWS 512
#define MAXNBC 256
#define EPT 16
#define BLK 256
#define EPB (BLK * EPT)      // 4096 edges per partition block

// ---------- embs fp32 -> fp16 ----------
__global__ __launch_bounds__(256) void k_conv(const float* __restrict__ embs,
                                              __half* __restrict__ embs16,
                                              int n_floats4) {
    int i = blockIdx.x * blockDim.x + threadIdx.x;
    if (i >= n_floats4) return;
    float4 f = reinterpret_cast<const float4*>(embs)[i];
    __half2 h0 = __floats2half2_rn(f.x, f.y);
    __half2 h1 = __floats2half2_rn(f.z, f.w);
    reinterpret_cast<__half2*>(embs16)[i * 2]     = h0;
    reinterpret_cast<__half2*>(embs16)[i * 2 + 1] = h1;
}

// ---------- coarse histogram ----------
__global__ __launch_bounds__(BLK) void k_hist(const int* __restrict__ row,
                                              int* __restrict__ cbcnt,
                                              int n_edges, int nbc) {
    __shared__ int l[MAXNBC];
    for (int j = threadIdx.x; j < nbc; j += BLK) l[j] = 0;
    __syncthreads();
    int base = blockIdx.x * EPB;
#pragma unroll
    for (int k = 0; k < EPT; ++k) {
        int e = base + k * BLK + threadIdx.x;
        if (e < n_edges) atomicAdd(&l[row[e] >> CSHIFT], 1);
    }
    __syncthreads();
    for (int j = threadIdx.x; j < nbc; j += BLK)
        if (l[j]) atomicAdd(&cbcnt[j], l[j]);
}

// ---------- exclusive scan over nbc (<=256) ----------
__global__ __launch_bounds__(256) void k_cscan(const int* __restrict__ cbcnt,
                                               int* __restrict__ cstart,
                                               int* __restrict__ gcur, int nbc) {
    __shared__ int s[256];
    int t = threadIdx.x;
    int v = (t < nbc) ? cbcnt[t] : 0;
    s[t] = v;
    __syncthreads();
    for (int off = 1; off < 256; off <<= 1) {
        int u = (t >= off) ? s[t - off] : 0;
        __syncthreads();
        s[t] += u;
        __syncthreads();
    }
    if (t < nbc) {
        int ex = s[t] - v;
        cstart[t] = ex;
        gcur[t] = ex;
        if (t == nbc - 1) cstart[nbc] = s[t];
    }
}

// ---------- pass 1: LDS-staged coarse partition, coalesced run writes ----------
__global__ __launch_bounds__(BLK) void k_part1(const int* __restrict__ row,
                                               const int* __restrict__ col,
                                               const float* __restrict__ val,
                                               int* __restrict__ gcur,
                                               int2* __restrict__ tmp1,
                                               int n_edges, int nbc) {
    __shared__ int2 stage[EPB];                 // 32 KB
    __shared__ int lcnt[MAXNBC], lstart[MAXNBC + 1], lcur[MAXNBC], lbase[MAXNBC];
    __shared__ int ssc[256];
    int tid = threadIdx.x;
    for (int j = tid; j < nbc; j += BLK) { lcnt[j] = 0; lcur[j] = 0; }
    __syncthreads();

    int base = blockIdx.x * EPB;
    int ne = n_edges - base; if (ne > EPB) ne = EPB;

    int r[EPT], c[EPT]; float v[EPT];
#pragma unroll
    for (int k = 0; k < EPT; ++k) {
        int e = base + k * BLK + tid;
        r[k] = -1;
        if (e < n_edges) {
            r[k] = row[e]; c[k] = col[e]; v[k] = val[e];
            atomicAdd(&lcnt[r[k] >> CSHIFT], 1);
        }
    }
    __syncthreads();
    // exclusive scan of lcnt
    int cv = (tid < nbc) ? lcnt[tid] : 0;
    ssc[tid] = cv;
    __syncthreads();
    for (int off = 1; off < 256; off <<= 1) {
        int u = (tid >= off) ? ssc[tid - off] : 0;
        __syncthreads();
        ssc[tid] += u;
        __syncthreads();
    }
    if (tid < nbc) {
        lstart[tid] = ssc[tid] - cv;
        if (cv) lbase[tid] = atomicAdd(&gcur[tid], cv);
        if (tid == nbc - 1) lstart[nbc] = ssc[tid];
    }
    __syncthreads();
    // place into LDS stage, bucket-sorted
#pragma unroll
    for (int k = 0; k < EPT; ++k) {
        if (r[k] >= 0) {
            int b = r[k] >> CSHIFT;
            int slot = lstart[b] + atomicAdd(&lcur[b], 1);
            stage[slot] = make_int2(((r[k] & (CROWS - 1)) << 17) | c[k],
                                    __float_as_int(v[k]));
        }
    }
    __syncthreads();
    // coalesced write-out: contiguous LDS -> contiguous global runs per bucket
    for (int i = tid; i < ne; i += BLK) {
        int lo = 0, hi = nbc;
        while (hi - lo > 1) {                    // upper_bound(lstart, i) - 1
            int mid = (lo + hi) >> 1;
            if (lstart[mid] <= i) lo = mid; else hi = mid;
        }
        tmp1[lbase[lo] + (i - lstart[lo])] = stage[i];
    }
}

// ---------- pass 2: per-coarse-bucket row sort -> pcv + CSR (int atomics only) ----------
__global__ __launch_bounds__(BLK) void k_part2(const int2* __restrict__ tmp1,
                                               const int* __restrict__ cstart,
                                               int2* __restrict__ pcv,
                                               int* __restrict__ row_start,
                                               int* __restrict__ row_cnt,
                                               int n_nodes) {
    __shared__ int rcnt[CROWS], rstart[CROWS], rcur[CROWS], ps[256];
    int b = blockIdx.x, tid = threadIdx.x;
    int base = cstart[b], end = cstart[b + 1];

    for (int j = tid; j < CROWS; j += BLK) { rcnt[j] = 0; rcur[j] = 0; }
    __syncthreads();
    for (int i = base + tid; i < end; i += BLK) {
        int lr = ((unsigned)tmp1[i].x) >> 17;
        atomicAdd(&rcnt[lr], 1);
    }
    __syncthreads();
    // exclusive scan over 512 counts (pairs per thread)
    int a0 = rcnt[2 * tid], a1 = rcnt[2 * tid + 1];
    int pv = a0 + a1;
    ps[tid] = pv;
    __syncthreads();
    for (int off = 1; off < 256; off <<= 1) {
        int u = (tid >= off) ? ps[tid - off] : 0;
        __syncthreads();
        ps[tid] += u;
        __syncthreads();
    }
    int ex = ps[tid] - pv;
    rstart[2 * tid] = ex;
    rstart[2 * tid + 1] = ex + a0;
    __syncthreads();
    // emit CSR metadata
    int gr0 = b << CSHIFT;
    for (int j = tid; j < CROWS; j += BLK) {
        int gr = gr0 + j;
        if (gr < n_nodes) {
            row_start[gr] = base + rstart[j];
            row_cnt[gr]   = rcnt[j];
        }
    }
    // scatter to row-sorted positions (block-private 130 KB window, L2-hot)
    for (int i = base + tid; i < end; i += BLK) {
        int2 p = tmp1[i];
        int lr = ((unsigned)p.x) >> 17;
        int pos = base + rstart[lr] + atomicAdd(&rcur[lr], 1);
        pcv[pos] = make_int2(p.x & 0x1FFFF, p.y);
    }
}

// ---------- accumulate: one wave per row, fp16 gathers (R4-proven) ----------
__global__ __launch_bounds__(256) void k_rows_h(const int2* __restrict__ pcv,
                                                const int* __restrict__ row_start,
                                                const int* __restrict__ row_cnt,
                                                const __half2* __restrict__ eb,
                                                float* __restrict__ out, int n_nodes) {
    int gtid = blockIdx.x * blockDim.x + threadIdx.x;
    int r = gtid >> 6;
    int lane = threadIdx.x & 63;
    if (r >= n_nodes) return;

    int start = row_start[r];
    int end   = start + row_cnt[r];

    float2 acc = make_float2(0.f, 0.f);

    int i = start;
    for (; i + 8 <= end; i += 8) {
        int2 p[8];
#pragma unroll
        for (int k = 0; k < 8; ++k) p[k] = pcv[i + k];
        __half2 h[8];
#pragma unroll
        for (int k = 0; k < 8; ++k) h[k] = eb[(size_t)p[k].x * 64 + lane];
#pragma unroll
        for (int k = 0; k < 8; ++k) {
            float v = __int_as_float(p[k].y);
            float2 f = __half22float2(h[k]);
            acc.x += v * f.x;
            acc.y += v * f.y;
        }
    }
    for (; i < end; ++i) {
        int2 p = pcv[i];
        float v = __int_as_float(p.y);
        float2 f = __half22float2(eb[(size_t)p.x * 64 + lane]);
        acc.x += v * f.x;
        acc.y += v * f.y;
    }
    reinterpret_cast<float2*>(out)[(size_t)r * 64 + lane] = acc;
}

// ---------- fallback: atomic scatter ----------
__global__ void gcn_scatter_atomic(const int* __restrict__ edge_row,
                                   const int* __restrict__ edge_col,
                                   const float* __restrict__ edge_val,
                                   const float* __restrict__ embs,
                                   float* __restrict__ out, int n_edges) {
    long long tid = (long long)blockIdx.x * blockDim.x + threadIdx.x;
    int sub = (int)(tid & 31);
    long long edge = tid >> 5;
    if (edge >= n_edges) return;
    int r = edge_row[edge];
    int c = edge_col[edge];
    float v = edge_val[edge];
    const float4* src = reinterpret_cast<const float4*>(embs + (size_t)c * D_FEAT);
    float4 m = src[sub];
    float* dst = out + (size_t)r * D_FEAT + (size_t)sub * 4;
    atomicAdd(dst + 0, m.x * v);
    atomicAdd(dst + 1, m.y * v);
    atomicAdd(dst + 2, m.z * v);
    atomicAdd(dst + 3, m.w * v);
}

extern "C" void kernel_launch(void* const* d_in, const int* in_sizes, int n_in,
                              void* d_out, int out_size, void* d_ws, size_t ws_size,
                              hipStream_t stream) {
    const int*   edge_row = (const int*)d_in[0];
    const int*   edge_col = (const int*)d_in[1];
    const float* edge_val = (const float*)d_in[2];
    const float* embs     = (const float*)d_in[3];
    float*       out      = (float*)d_out;

    const int n_edges = in_sizes[0];
    const int n_nodes = out_size / D_FEAT;
    const int nbc = (n_nodes + CROWS - 1) >> CSHIFT;

    // Workspace layout
    char* ws = (char*)d_ws;
    const size_t off_pcv       = 0;
    const size_t off_row_start = off_pcv + (size_t)n_edges * 8;
    const size_t off_row_cnt   = off_row_start + (size_t)n_nodes * 4;
    const size_t off_cbcnt     = off_row_cnt + (size_t)n_nodes * 4;
    const size_t off_cstart    = off_cbcnt + (size_t)MAXNBC * 4;
    const size_t off_gcur      = off_cstart + (size_t)(MAXNBC + 1) * 4;
    const size_t off_embs16    = (off_gcur + (size_t)MAXNBC * 4 + 15) & ~(size_t)15;
    const size_t full_ws       = off_embs16 + (size_t)n_nodes * D_FEAT * 2;

    // tmp1 aliases d_out (consumed by k_part2 before k_rows_h writes out).
    bool tmp_fits = ((size_t)n_edges * 8 <= (size_t)out_size * 4);
    bool packs_ok = (n_nodes <= 131072) && (nbc <= MAXNBC);  // 17-bit col, 9-bit lr

    if (ws_size < full_ws || !tmp_fits || !packs_ok) {
        hipMemsetAsync(d_out, 0, (size_t)out_size * sizeof(float), stream);
        long long total = (long long)n_edges * 32;
        int blocks = (int)((total + 255) / 256);
        gcn_scatter_atomic<<<blocks, 256, 0, stream>>>(edge_row, edge_col, edge_val,
                                                       embs, out, n_edges);
        return;
    }

    int2*   pcv       = (int2*)(ws + off_pcv);
    int*    row_start = (int*)(ws + off_row_start);
    int*    row_cnt   = (int*)(ws + off_row_cnt);
    int*    cbcnt     = (int*)(ws + off_cbcnt);
    int*    cstart    = (int*)(ws + off_cstart);
    int*    gcur      = (int*)(ws + off_gcur);
    __half* embs16    = (__half*)(ws + off_embs16);
    int2*   tmp1      = (int2*)d_out;

    hipMemsetAsync(cbcnt, 0, (size_t)MAXNBC * 4, stream);

    const int nchunks = (n_edges + EPB - 1) / EPB;
    const int nf4 = n_nodes * (D_FEAT / 4);

    k_conv<<<(nf4 + 255) / 256, 256, 0, stream>>>(embs, embs16, nf4);
    k_hist<<<nchunks, BLK, 0, stream>>>(edge_row, cbcnt, n_edges, nbc);
    k_cscan<<<1, 256, 0, stream>>>(cbcnt, cstart, gcur, nbc);
    k_part1<<<nchunks, BLK, 0, stream>>>(edge_row, edge_col, edge_val,
                                         gcur, tmp1, n_edges, nbc);
    k_part2<<<nbc, BLK, 0, stream>>>(tmp1, cstart, pcv, row_start, row_cnt, n_nodes);

    long long rows_threads = (long long)n_nodes * 64;
    int rblocks = (int)((rows_threads + 255) / 256);
    k_rows_h<<<rblocks, 256, 0, stream>>>(pcv, row_start, row_cnt,
                                          (const __half2*)embs16, out, n_nodes);
}